// Round 3
// baseline (3476.855 us; speedup 1.0000x reference)
//
#include <hip/hip_runtime.h>
#include <math.h>

// GCN 2-layer forward:
//   h1 = relu(Dinv (A+I) Dinv X W1 + b1)
//   o  = Dinv (A+I) Dinv h1 W2 + b2
//   out = log_softmax(o, axis=1)
// Factorization: g = (x@W)*dinv ; out = dinv*(scatter_add(g[src]) + g) + b
// deg[i] = in_degree(i) + 1  (self-loop), dinv = rsqrt(deg)  (deg >= 1 always)

#define BLK 256

// ws is poisoned 0xAA before every timed call -> re-init everything here.
// i ranges over n*16: zeroes agg1 fully; first n*4 threads zero agg2; first n set deg=1.
__global__ void __launch_bounds__(BLK) k_init(float* __restrict__ deg,
                                              float* __restrict__ agg1,
                                              float* __restrict__ agg2, int n) {
    int i = blockIdx.x * BLK + threadIdx.x;
    if (i < n * 16) agg1[i] = 0.0f;
    if (i < n * 4)  agg2[i] = 0.0f;
    if (i < n)      deg[i]  = 1.0f;   // self-loop contributes 1
}

__global__ void __launch_bounds__(BLK) k_deg(const int* __restrict__ dst,
                                             float* __restrict__ deg, int E) {
    int e = blockIdx.x * BLK + threadIdx.x;
    if (e < E) atomicAdd(&deg[dst[e]], 1.0f);
}

// dinv = rsqrt(deg) (in place); g1[i][:] = (x[i] @ W1) * dinv[i]   (4 -> 16)
__global__ void __launch_bounds__(BLK) k_node1(const float* __restrict__ x,
                                               const float* __restrict__ W1,
                                               float* __restrict__ deg,
                                               float* __restrict__ g1, int n) {
    int i = blockIdx.x * BLK + threadIdx.x;
    if (i >= n) return;
    float di = rsqrtf(deg[i]);
    deg[i] = di;  // repurpose buffer as dinv
    float4 xv = reinterpret_cast<const float4*>(x)[i];
    float4* out = reinterpret_cast<float4*>(g1 + (size_t)i * 16);
#pragma unroll
    for (int q = 0; q < 4; ++q) {
        float4 h;
        float* hp = reinterpret_cast<float*>(&h);
#pragma unroll
        for (int r = 0; r < 4; ++r) {
            int j = q * 4 + r;
            // W1 is [4][16] row-major; indices are wave-uniform -> scalar-load broadcast
            hp[r] = (xv.x * W1[j] + xv.y * W1[16 + j] +
                     xv.z * W1[32 + j] + xv.w * W1[48 + j]) * di;
        }
        out[q] = h;
    }
}

// layer-1 edge pass: agg1[dst] += g1[src]  (16 floats / edge; g1 row = one 64B line)
__global__ void __launch_bounds__(BLK) k_edge1(const int* __restrict__ src,
                                               const int* __restrict__ dst,
                                               const float* __restrict__ g1,
                                               float* __restrict__ agg1, int E) {
    int e = blockIdx.x * BLK + threadIdx.x;
    if (e >= E) return;
    int s = src[e], d = dst[e];
    const float4* gs = reinterpret_cast<const float4*>(g1 + (size_t)s * 16);
    float4 v0 = gs[0], v1 = gs[1], v2 = gs[2], v3 = gs[3];
    float* a = agg1 + (size_t)d * 16;
    atomicAdd(a + 0,  v0.x); atomicAdd(a + 1,  v0.y);
    atomicAdd(a + 2,  v0.z); atomicAdd(a + 3,  v0.w);
    atomicAdd(a + 4,  v1.x); atomicAdd(a + 5,  v1.y);
    atomicAdd(a + 6,  v1.z); atomicAdd(a + 7,  v1.w);
    atomicAdd(a + 8,  v2.x); atomicAdd(a + 9,  v2.y);
    atomicAdd(a + 10, v2.z); atomicAdd(a + 11, v2.w);
    atomicAdd(a + 12, v3.x); atomicAdd(a + 13, v3.y);
    atomicAdd(a + 14, v3.z); atomicAdd(a + 15, v3.w);
}

// t = relu(dinv*(agg1+g1)+b1);  g2[i][:] = (t @ W2) * dinv   (16 -> 4)
__global__ void __launch_bounds__(BLK) k_node2(const float* __restrict__ dinv,
                                               const float* __restrict__ g1,
                                               const float* __restrict__ agg1,
                                               const float* __restrict__ b1,
                                               const float* __restrict__ W2,
                                               float* __restrict__ g2, int n) {
    int i = blockIdx.x * BLK + threadIdx.x;
    if (i >= n) return;
    float di = dinv[i];
    const float4* gp = reinterpret_cast<const float4*>(g1 + (size_t)i * 16);
    const float4* ap = reinterpret_cast<const float4*>(agg1 + (size_t)i * 16);
    float o0 = 0.f, o1 = 0.f, o2 = 0.f, o3 = 0.f;
#pragma unroll
    for (int q = 0; q < 4; ++q) {
        float4 g = gp[q], a = ap[q];
        float t[4] = { g.x + a.x, g.y + a.y, g.z + a.z, g.w + a.w };
#pragma unroll
        for (int r = 0; r < 4; ++r) {
            int j = q * 4 + r;
            float v = di * t[r] + b1[j];
            v = v > 0.f ? v : 0.f;
            o0 += v * W2[j * 4 + 0];
            o1 += v * W2[j * 4 + 1];
            o2 += v * W2[j * 4 + 2];
            o3 += v * W2[j * 4 + 3];
        }
    }
    float4 out = { o0 * di, o1 * di, o2 * di, o3 * di };
    reinterpret_cast<float4*>(g2)[i] = out;
}

// layer-2 edge pass: agg2[dst] += g2[src]  (4 floats / edge)
__global__ void __launch_bounds__(BLK) k_edge2(const int* __restrict__ src,
                                               const int* __restrict__ dst,
                                               const float* __restrict__ g2,
                                               float* __restrict__ agg2, int E) {
    int e = blockIdx.x * BLK + threadIdx.x;
    if (e >= E) return;
    int s = src[e], d = dst[e];
    float4 v = reinterpret_cast<const float4*>(g2)[s];
    float* a = agg2 + (size_t)d * 4;
    atomicAdd(a + 0, v.x); atomicAdd(a + 1, v.y);
    atomicAdd(a + 2, v.z); atomicAdd(a + 3, v.w);
}

// o = dinv*(agg2+g2)+b2; out = log_softmax(o)
__global__ void __launch_bounds__(BLK) k_node3(const float* __restrict__ dinv,
                                               const float* __restrict__ g2,
                                               const float* __restrict__ agg2,
                                               const float* __restrict__ b2,
                                               float* __restrict__ out, int n) {
    int i = blockIdx.x * BLK + threadIdx.x;
    if (i >= n) return;
    float di = dinv[i];
    float4 g = reinterpret_cast<const float4*>(g2)[i];
    float4 a = reinterpret_cast<const float4*>(agg2)[i];
    float o0 = di * (g.x + a.x) + b2[0];
    float o1 = di * (g.y + a.y) + b2[1];
    float o2 = di * (g.z + a.z) + b2[2];
    float o3 = di * (g.w + a.w) + b2[3];
    float m = fmaxf(fmaxf(o0, o1), fmaxf(o2, o3));
    float s = expf(o0 - m) + expf(o1 - m) + expf(o2 - m) + expf(o3 - m);
    float l = m + logf(s);
    float4 r = { o0 - l, o1 - l, o2 - l, o3 - l };
    reinterpret_cast<float4*>(out)[i] = r;
}

extern "C" void kernel_launch(void* const* d_in, const int* in_sizes, int n_in,
                              void* d_out, int out_size, void* d_ws, size_t ws_size,
                              hipStream_t stream) {
    const float* x  = (const float*)d_in[0];
    const float* W1 = (const float*)d_in[1];
    const float* b1 = (const float*)d_in[2];
    const float* W2 = (const float*)d_in[3];
    const float* b2 = (const float*)d_in[4];
    const int*   ei = (const int*)d_in[5];

    const int n = in_sizes[0] / 4;   // 100000
    const int E = in_sizes[5] / 2;   // 3200000
    const int* src = ei;
    const int* dst = ei + E;

    // workspace layout (all 64B-aligned; total ~16.4 MB)
    char* ws = (char*)d_ws;
    float* deg  = (float*)(ws);                                   // n      -> becomes dinv
    float* g1   = (float*)(ws + (size_t)n * 4);                   // n*16
    float* agg1 = (float*)(ws + (size_t)n * 4 + (size_t)n * 64);  // n*16
    float* g2   = (float*)(ws + (size_t)n * 4 + (size_t)n * 128); // n*4
    float* agg2 = (float*)(ws + (size_t)n * 4 + (size_t)n * 144); // n*4
    float* out  = (float*)d_out;

    const int nB = (n + BLK - 1) / BLK;
    const int eB = (E + BLK - 1) / BLK;
    const int iB = (16 * n + BLK - 1) / BLK;

    k_init  <<<iB, BLK, 0, stream>>>(deg, agg1, agg2, n);
    k_deg   <<<eB, BLK, 0, stream>>>(dst, deg, E);
    k_node1 <<<nB, BLK, 0, stream>>>(x, W1, deg, g1, n);
    k_edge1 <<<eB, BLK, 0, stream>>>(src, dst, g1, agg1, E);
    k_node2 <<<nB, BLK, 0, stream>>>(deg, g1, agg1, b1, W2, g2, n);
    k_edge2 <<<eB, BLK, 0, stream>>>(src, dst, g2, agg2, E);
    k_node3 <<<nB, BLK, 0, stream>>>(deg, g2, agg2, b2, out, n);
}

// Round 5
// 1483.558 us; speedup vs baseline: 2.3436x; 2.3436x over previous
//
#include <hip/hip_runtime.h>
#include <math.h>

// GCN 2-layer forward, atomic-minimized:
//   out = log_softmax( Dinv(A+I)Dinv' relu( Dinv(A+I)Dinv' X W1 + b1 ) W2 + b2 )
// Key algebraic move: layer-1 aggregation commutes with W1:
//   sum_s (x[s]@W1)*dinv[s] = (sum_s x[s]*dinv[s]) @ W1
// so BOTH edge passes scatter only 4 floats/edge (min(in,out) dim).
// deg[i] = in_degree(i)+1 (self-loop); dinv = rsqrt(deg).
// Atomics: integer for degree, unsafeAtomicAdd (native global_atomic_add_f32,
// no CAS loop) for feature aggregation.

#define BLK 256

// ws poisoned 0xAA every call -> re-init. i ranges over n*4.
__global__ void __launch_bounds__(BLK) k_init(int* __restrict__ deg,
                                              float* __restrict__ agg1,
                                              float* __restrict__ agg2, int n) {
    int i = blockIdx.x * BLK + threadIdx.x;
    if (i < n * 4) { agg1[i] = 0.0f; agg2[i] = 0.0f; }
    if (i < n)     deg[i] = 1;   // self-loop contributes 1
}

__global__ void __launch_bounds__(BLK) k_deg(const int* __restrict__ dst,
                                             int* __restrict__ deg, int E) {
    int e = blockIdx.x * BLK + threadIdx.x;
    if (e < E) atomicAdd(&deg[dst[e]], 1);   // native int atomic
}

// dinv = rsqrt(deg); xd[i] = x[i] * dinv[i]   (4-dim)
__global__ void __launch_bounds__(BLK) k_node1(const float* __restrict__ x,
                                               const int* __restrict__ deg,
                                               float* __restrict__ dinv,
                                               float* __restrict__ xd, int n) {
    int i = blockIdx.x * BLK + threadIdx.x;
    if (i >= n) return;
    float di = rsqrtf((float)deg[i]);
    dinv[i] = di;
    float4 xv = reinterpret_cast<const float4*>(x)[i];
    float4 o = { xv.x * di, xv.y * di, xv.z * di, xv.w * di };
    reinterpret_cast<float4*>(xd)[i] = o;
}

// layer-1 edge pass: agg1[dst] += xd[src]   (4 floats/edge, HW f32 atomics)
__global__ void __launch_bounds__(BLK) k_edge1(const int* __restrict__ src,
                                               const int* __restrict__ dst,
                                               const float* __restrict__ xd,
                                               float* __restrict__ agg1, int E) {
    int e = blockIdx.x * BLK + threadIdx.x;
    if (e >= E) return;
    int s = src[e], d = dst[e];
    float4 v = reinterpret_cast<const float4*>(xd)[s];
    float* a = agg1 + (size_t)d * 4;
    unsafeAtomicAdd(a + 0, v.x);
    unsafeAtomicAdd(a + 1, v.y);
    unsafeAtomicAdd(a + 2, v.z);
    unsafeAtomicAdd(a + 3, v.w);
}

// t = relu(dinv*((agg1+xd)@W1)+b1)  [4->16];  g2 = (t@W2)*dinv  [16->4]
__global__ void __launch_bounds__(BLK) k_node2(const float* __restrict__ dinv,
                                               const float* __restrict__ xd,
                                               const float* __restrict__ agg1,
                                               const float* __restrict__ W1,
                                               const float* __restrict__ b1,
                                               const float* __restrict__ W2,
                                               float* __restrict__ g2, int n) {
    int i = blockIdx.x * BLK + threadIdx.x;
    if (i >= n) return;
    float di = dinv[i];
    float4 xv = reinterpret_cast<const float4*>(xd)[i];
    float4 av = reinterpret_cast<const float4*>(agg1)[i];
    float sx = xv.x + av.x, sy = xv.y + av.y, sz = xv.z + av.z, sw = xv.w + av.w;
    float o0 = 0.f, o1 = 0.f, o2 = 0.f, o3 = 0.f;
#pragma unroll
    for (int j = 0; j < 16; ++j) {
        // W1 [4][16] row-major, wave-uniform index -> scalar-load broadcast
        float h = sx * W1[j] + sy * W1[16 + j] + sz * W1[32 + j] + sw * W1[48 + j];
        float v = di * h + b1[j];
        v = v > 0.f ? v : 0.f;   // relu
        o0 += v * W2[j * 4 + 0];
        o1 += v * W2[j * 4 + 1];
        o2 += v * W2[j * 4 + 2];
        o3 += v * W2[j * 4 + 3];
    }
    float4 out = { o0 * di, o1 * di, o2 * di, o3 * di };
    reinterpret_cast<float4*>(g2)[i] = out;
}

// layer-2 edge pass: agg2[dst] += g2[src]   (4 floats/edge)
__global__ void __launch_bounds__(BLK) k_edge2(const int* __restrict__ src,
                                               const int* __restrict__ dst,
                                               const float* __restrict__ g2,
                                               float* __restrict__ agg2, int E) {
    int e = blockIdx.x * BLK + threadIdx.x;
    if (e >= E) return;
    int s = src[e], d = dst[e];
    float4 v = reinterpret_cast<const float4*>(g2)[s];
    float* a = agg2 + (size_t)d * 4;
    unsafeAtomicAdd(a + 0, v.x);
    unsafeAtomicAdd(a + 1, v.y);
    unsafeAtomicAdd(a + 2, v.z);
    unsafeAtomicAdd(a + 3, v.w);
}

// o = dinv*(agg2+g2)+b2; out = log_softmax(o)
__global__ void __launch_bounds__(BLK) k_node3(const float* __restrict__ dinv,
                                               const float* __restrict__ g2,
                                               const float* __restrict__ agg2,
                                               const float* __restrict__ b2,
                                               float* __restrict__ out, int n) {
    int i = blockIdx.x * BLK + threadIdx.x;
    if (i >= n) return;
    float di = dinv[i];
    float4 g = reinterpret_cast<const float4*>(g2)[i];
    float4 a = reinterpret_cast<const float4*>(agg2)[i];
    float o0 = di * (g.x + a.x) + b2[0];
    float o1 = di * (g.y + a.y) + b2[1];
    float o2 = di * (g.z + a.z) + b2[2];
    float o3 = di * (g.w + a.w) + b2[3];
    float m = fmaxf(fmaxf(o0, o1), fmaxf(o2, o3));
    float s = expf(o0 - m) + expf(o1 - m) + expf(o2 - m) + expf(o3 - m);
    float l = m + logf(s);
    float4 r = { o0 - l, o1 - l, o2 - l, o3 - l };
    reinterpret_cast<float4*>(out)[i] = r;
}

extern "C" void kernel_launch(void* const* d_in, const int* in_sizes, int n_in,
                              void* d_out, int out_size, void* d_ws, size_t ws_size,
                              hipStream_t stream) {
    const float* x  = (const float*)d_in[0];
    const float* W1 = (const float*)d_in[1];
    const float* b1 = (const float*)d_in[2];
    const float* W2 = (const float*)d_in[3];
    const float* b2 = (const float*)d_in[4];
    const int*   ei = (const int*)d_in[5];

    const int n = in_sizes[0] / 4;   // 100000
    const int E = in_sizes[5] / 2;   // 3200000
    const int* src = ei;
    const int* dst = ei + E;

    // workspace layout (16B-aligned; ~7.2 MB total)
    char* ws = (char*)d_ws;
    int*   deg  = (int*)(ws);                                      // n
    float* dinv = (float*)(ws + (size_t)n * 4);                    // n
    float* xd   = (float*)(ws + (size_t)n * 8);                    // n*4
    float* agg1 = (float*)(ws + (size_t)n * 8 + (size_t)n * 16);   // n*4
    float* g2   = (float*)(ws + (size_t)n * 8 + (size_t)n * 32);   // n*4
    float* agg2 = (float*)(ws + (size_t)n * 8 + (size_t)n * 48);   // n*4
    float* out  = (float*)d_out;

    const int nB = (n + BLK - 1) / BLK;
    const int eB = (E + BLK - 1) / BLK;
    const int iB = (4 * n + BLK - 1) / BLK;

    k_init  <<<iB, BLK, 0, stream>>>(deg, agg1, agg2, n);
    k_deg   <<<eB, BLK, 0, stream>>>(dst, deg, E);
    k_node1 <<<nB, BLK, 0, stream>>>(x, deg, dinv, xd, n);
    k_edge1 <<<eB, BLK, 0, stream>>>(src, dst, xd, agg1, E);
    k_node2 <<<nB, BLK, 0, stream>>>(dinv, xd, agg1, W1, b1, W2, g2, n);
    k_edge2 <<<eB, BLK, 0, stream>>>(src, dst, g2, agg2, E);
    k_node3 <<<nB, BLK, 0, stream>>>(dinv, g2, agg2, b2, out, n);
}

// Round 6
// 529.649 us; speedup vs baseline: 6.5645x; 2.8010x over previous
//
#include <hip/hip_runtime.h>
#include <math.h>

// GCN 2-layer forward, zero f32 atomics (CSR-gather):
//   out = log_softmax( Dinv(A+I)Dinv' relu( Dinv(A+I)Dinv' X W1 + b1 ) W2 + b2 )
// Aggregation commutes with W1 (4-dim), so both layers aggregate 4-vectors.
// Build incoming-edge CSR once (cnt/scan/fill with int atomics), then each
// layer is a per-node gather-reduce with NO atomics. Round-5 counters showed
// f32 atomic write-through (32B/atomic to HBM) was 86% of runtime.

#define BLK 256

__global__ void __launch_bounds__(BLK) k_zero(int* __restrict__ cnt, int n) {
    int i = blockIdx.x * BLK + threadIdx.x;
    if (i < n) cnt[i] = 0;
}

// in-degree histogram (native int atomics)
__global__ void __launch_bounds__(BLK) k_deg(const int* __restrict__ dst,
                                             int* __restrict__ cnt, int E) {
    int e = blockIdx.x * BLK + threadIdx.x;
    if (e < E) atomicAdd(&cnt[dst[e]], 1);
}

// per-block sums of cnt
__global__ void __launch_bounds__(BLK) k_scanA(const int* __restrict__ cnt,
                                               int* __restrict__ bsum, int n) {
    __shared__ int sh[BLK];
    int i = blockIdx.x * BLK + threadIdx.x;
    sh[threadIdx.x] = (i < n) ? cnt[i] : 0;
    __syncthreads();
    for (int off = BLK >> 1; off > 0; off >>= 1) {
        if (threadIdx.x < off) sh[threadIdx.x] += sh[threadIdx.x + off];
        __syncthreads();
    }
    if (threadIdx.x == 0) bsum[blockIdx.x] = sh[0];
}

// exclusive scan of bsum[nb], nb <= 1024, single block
__global__ void __launch_bounds__(1024) k_scanB(const int* __restrict__ bsum,
                                                int* __restrict__ boff, int nb) {
    __shared__ int sh[1024];
    int t = threadIdx.x;
    int v = (t < nb) ? bsum[t] : 0;
    sh[t] = v; __syncthreads();
    for (int off = 1; off < 1024; off <<= 1) {
        int u = (t >= off) ? sh[t - off] : 0;
        __syncthreads();
        sh[t] += u;
        __syncthreads();
    }
    if (t < nb) boff[t] = sh[t] - v;   // exclusive
}

// per-block exclusive scan + block offset -> cur (fill cursors / row starts);
// fused node-1: dinv = rsqrt(cnt+1), xd = x * dinv
__global__ void __launch_bounds__(BLK) k_scanC(const int* __restrict__ cnt,
                                               const int* __restrict__ boff,
                                               const float* __restrict__ x,
                                               int* __restrict__ cur,
                                               float* __restrict__ dinv,
                                               float* __restrict__ xd, int n) {
    __shared__ int sh[BLK];
    int t = threadIdx.x;
    int i = blockIdx.x * BLK + t;
    int v = (i < n) ? cnt[i] : 0;
    sh[t] = v; __syncthreads();
    for (int off = 1; off < BLK; off <<= 1) {
        int u = (t >= off) ? sh[t - off] : 0;
        __syncthreads();
        sh[t] += u;
        __syncthreads();
    }
    if (i < n) {
        cur[i] = sh[t] - v + boff[blockIdx.x];      // global exclusive scan
        float di = rsqrtf((float)(v + 1));          // +1 self-loop
        dinv[i] = di;
        float4 xv = reinterpret_cast<const float4*>(x)[i];
        float4 o = { xv.x * di, xv.y * di, xv.z * di, xv.w * di };
        reinterpret_cast<float4*>(xd)[i] = o;
    }
}

// CSR fill: eid[cur[dst]++] = src   (3.2M int atomic-returns; every slot written)
__global__ void __launch_bounds__(BLK) k_fill(const int* __restrict__ src,
                                              const int* __restrict__ dst,
                                              int* __restrict__ cur,
                                              int* __restrict__ eid, int E) {
    int e = blockIdx.x * BLK + threadIdx.x;
    if (e >= E) return;
    int pos = atomicAdd(&cur[dst[e]], 1);
    eid[pos] = src[e];
}

// layer-1 gather + full node-2 math (no atomics):
//   s = xd[i] + sum_j xd[eid[..]];  h=relu(di*(s@W1)+b1);  g2=(h@W2)*di
__global__ void __launch_bounds__(BLK) k_g1(const int* __restrict__ cnt,
                                            const int* __restrict__ cur,
                                            const int* __restrict__ eid,
                                            const float* __restrict__ dinv,
                                            const float* __restrict__ xd,
                                            const float* __restrict__ W1,
                                            const float* __restrict__ b1,
                                            const float* __restrict__ W2,
                                            float* __restrict__ g2, int n) {
    int i = blockIdx.x * BLK + threadIdx.x;
    if (i >= n) return;
    float di = dinv[i];
    int c = cnt[i];
    int start = cur[i] - c;          // cur was advanced by exactly c in k_fill
    float4 s = reinterpret_cast<const float4*>(xd)[i];   // self-loop term
    for (int j = 0; j < c; ++j) {
        int sidx = eid[start + j];
        float4 v = reinterpret_cast<const float4*>(xd)[sidx];
        s.x += v.x; s.y += v.y; s.z += v.z; s.w += v.w;
    }
    float o0 = 0.f, o1 = 0.f, o2 = 0.f, o3 = 0.f;
#pragma unroll
    for (int j = 0; j < 16; ++j) {
        // W1 [4][16] row-major; wave-uniform index -> scalar-load broadcast
        float h = s.x * W1[j] + s.y * W1[16 + j] + s.z * W1[32 + j] + s.w * W1[48 + j];
        float v = di * h + b1[j];
        v = v > 0.f ? v : 0.f;       // relu
        o0 += v * W2[j * 4 + 0];
        o1 += v * W2[j * 4 + 1];
        o2 += v * W2[j * 4 + 2];
        o3 += v * W2[j * 4 + 3];
    }
    float4 out = { o0 * di, o1 * di, o2 * di, o3 * di };
    reinterpret_cast<float4*>(g2)[i] = out;
}

// layer-2 gather + bias + log_softmax (no atomics)
__global__ void __launch_bounds__(BLK) k_g2(const int* __restrict__ cnt,
                                            const int* __restrict__ cur,
                                            const int* __restrict__ eid,
                                            const float* __restrict__ dinv,
                                            const float* __restrict__ g2,
                                            const float* __restrict__ b2,
                                            float* __restrict__ out, int n) {
    int i = blockIdx.x * BLK + threadIdx.x;
    if (i >= n) return;
    float di = dinv[i];
    int c = cnt[i];
    int start = cur[i] - c;
    float4 s = reinterpret_cast<const float4*>(g2)[i];   // self-loop term
    for (int j = 0; j < c; ++j) {
        int sidx = eid[start + j];
        float4 v = reinterpret_cast<const float4*>(g2)[sidx];
        s.x += v.x; s.y += v.y; s.z += v.z; s.w += v.w;
    }
    float o0 = di * s.x + b2[0];
    float o1 = di * s.y + b2[1];
    float o2 = di * s.z + b2[2];
    float o3 = di * s.w + b2[3];
    float m = fmaxf(fmaxf(o0, o1), fmaxf(o2, o3));
    float sm = expf(o0 - m) + expf(o1 - m) + expf(o2 - m) + expf(o3 - m);
    float l = m + logf(sm);
    float4 r = { o0 - l, o1 - l, o2 - l, o3 - l };
    reinterpret_cast<float4*>(out)[i] = r;
}

extern "C" void kernel_launch(void* const* d_in, const int* in_sizes, int n_in,
                              void* d_out, int out_size, void* d_ws, size_t ws_size,
                              hipStream_t stream) {
    const float* x  = (const float*)d_in[0];
    const float* W1 = (const float*)d_in[1];
    const float* b1 = (const float*)d_in[2];
    const float* W2 = (const float*)d_in[3];
    const float* b2 = (const float*)d_in[4];
    const int*   ei = (const int*)d_in[5];

    const int n = in_sizes[0] / 4;   // 100000
    const int E = in_sizes[5] / 2;   // 3200000
    const int* src = ei;
    const int* dst = ei + E;

    // workspace layout (16B-aligned; ~17.2 MB). All buffers fully rewritten
    // every call (ws poisoned 0xAA).
    char* ws = (char*)d_ws;
    size_t off = 0;
    float* xd   = (float*)(ws + off); off += (size_t)n * 16;   // n*4 f32
    float* g2   = (float*)(ws + off); off += (size_t)n * 16;   // n*4 f32
    int*   eid  = (int*)  (ws + off); off += (size_t)E * 4;    // E ints
    int*   cnt  = (int*)  (ws + off); off += (size_t)n * 4;
    int*   cur  = (int*)  (ws + off); off += (size_t)n * 4;
    float* dinv = (float*)(ws + off); off += (size_t)n * 4;
    int*   bsum = (int*)  (ws + off); off += 1024 * 4;
    int*   boff = (int*)  (ws + off); off += 1024 * 4;
    float* out  = (float*)d_out;

    const int nB = (n + BLK - 1) / BLK;   // 391
    const int eB = (E + BLK - 1) / BLK;   // 12500

    k_zero <<<nB, BLK, 0, stream>>>(cnt, n);
    k_deg  <<<eB, BLK, 0, stream>>>(dst, cnt, E);
    k_scanA<<<nB, BLK, 0, stream>>>(cnt, bsum, n);
    k_scanB<<<1, 1024, 0, stream>>>(bsum, boff, nB);
    k_scanC<<<nB, BLK, 0, stream>>>(cnt, boff, x, cur, dinv, xd, n);
    k_fill <<<eB, BLK, 0, stream>>>(src, dst, cur, eid, E);
    k_g1   <<<nB, BLK, 0, stream>>>(cnt, cur, eid, dinv, xd, W1, b1, W2, g2, n);
    k_g2   <<<nB, BLK, 0, stream>>>(cnt, cur, eid, dinv, g2, b2, out, n);
}

// Round 7
// 325.002 us; speedup vs baseline: 10.6980x; 1.6297x over previous
//
#include <hip/hip_runtime.h>
#include <math.h>

// GCN 2-layer forward with ZERO global atomics.
// Round-6 counters: k_fill (CSR scatter) = 278us at 195MB HBM write-through;
// every scattered global atomic/store costs a 32B sector at ~20Gop/s.
// Fix: bucket edges by dst (dst>>8, 256 nodes/bucket) with LDS histograms +
// LDS cursors (binA/scan/binB), then do degree-count and both layer
// aggregations entirely in LDS per bucket. All global traffic is streaming.
//
//   out = log_softmax( Dinv(A+I)Dinv' relu( Dinv(A+I)Dinv' X W1 + b1 ) W2 + b2 )
// Aggregation commutes with W1, so both layers aggregate 4-vectors.

#define BLK   256
#define G     256      // number of binning blocks (chunks)
#define SH    8        // log2(nodes per bucket)
#define S     256      // nodes per bucket
#define MAXNB 512      // LDS table capacity (NB = ceil(n/S) = 391 <= 512)

// ---- pass A: per-chunk bucket histogram (LDS atomics only) ----
__global__ void __launch_bounds__(BLK) k_binA(const int* __restrict__ dst,
                                              int* __restrict__ gh,
                                              int E, int NB, int chunk) {
    __shared__ int hist[MAXNB];
    int g = blockIdx.x, t = threadIdx.x;
    for (int j = t; j < NB; j += BLK) hist[j] = 0;
    __syncthreads();
    int e0 = g * chunk, e1 = min(e0 + chunk, E);
    for (int e = e0 + t; e < e1; e += BLK)
        atomicAdd(&hist[dst[e] >> SH], 1);
    __syncthreads();
    for (int j = t; j < NB; j += BLK) gh[j * G + g] = hist[j];  // [bucket][block]
}

// ---- 3-kernel exclusive scan over m = NB*G elements (in place) ----
__global__ void __launch_bounds__(BLK) k_scanA(const int* __restrict__ a,
                                               int* __restrict__ bsum, int m) {
    __shared__ int sh[BLK];
    int i = blockIdx.x * BLK + threadIdx.x;
    sh[threadIdx.x] = (i < m) ? a[i] : 0;
    __syncthreads();
    for (int off = BLK >> 1; off > 0; off >>= 1) {
        if (threadIdx.x < off) sh[threadIdx.x] += sh[threadIdx.x + off];
        __syncthreads();
    }
    if (threadIdx.x == 0) bsum[blockIdx.x] = sh[0];
}

__global__ void __launch_bounds__(1024) k_scanB(const int* __restrict__ bsum,
                                                int* __restrict__ boff, int nb) {
    __shared__ int sh[1024];
    int t = threadIdx.x;
    int v = (t < nb) ? bsum[t] : 0;
    sh[t] = v; __syncthreads();
    for (int off = 1; off < 1024; off <<= 1) {
        int u = (t >= off) ? sh[t - off] : 0;
        __syncthreads();
        sh[t] += u;
        __syncthreads();
    }
    if (t < nb) boff[t] = sh[t] - v;   // exclusive
}

__global__ void __launch_bounds__(BLK) k_scanC(int* __restrict__ a,
                                               const int* __restrict__ boff, int m) {
    __shared__ int sh[BLK];
    int t = threadIdx.x;
    int i = blockIdx.x * BLK + t;
    int v = (i < m) ? a[i] : 0;
    sh[t] = v; __syncthreads();
    for (int off = 1; off < BLK; off <<= 1) {
        int u = (t >= off) ? sh[t - off] : 0;
        __syncthreads();
        sh[t] += u;
        __syncthreads();
    }
    if (i < m) a[i] = sh[t] - v + boff[blockIdx.x];   // global exclusive scan
}

// ---- pass B: scatter packed edges into bucket-contiguous runs (LDS cursors) ----
// word = src | (dst&255)<<24   (src < 2^24)
__global__ void __launch_bounds__(BLK) k_binB(const int* __restrict__ src,
                                              const int* __restrict__ dst,
                                              const int* __restrict__ offs,
                                              int* __restrict__ words,
                                              int E, int NB, int chunk) {
    __shared__ int cur[MAXNB];
    int g = blockIdx.x, t = threadIdx.x;
    for (int j = t; j < NB; j += BLK) cur[j] = offs[j * G + g];
    __syncthreads();
    int e0 = g * chunk, e1 = min(e0 + chunk, E);
    for (int e = e0 + t; e < e1; e += BLK) {
        int d = dst[e];
        int b = d >> SH;
        int pos = atomicAdd(&cur[b], 1);           // LDS atomic
        words[pos] = src[e] | ((d & (S - 1)) << 24);
    }
}

// ---- per-bucket degree count (LDS) + fused dinv/xd ----
__global__ void __launch_bounds__(BLK) k_bdeg(const int* __restrict__ words,
                                              const int* __restrict__ offs,
                                              const float* __restrict__ x,
                                              float* __restrict__ dinv,
                                              float* __restrict__ xd,
                                              int n, int E, int NB) {
    __shared__ int cnt[S];
    int b = blockIdx.x, t = threadIdx.x;
    cnt[t] = 0;
    __syncthreads();
    int e0 = offs[b * G];
    int e1 = (b + 1 < NB) ? offs[(b + 1) * G] : E;
    for (int e = e0 + t; e < e1; e += BLK)
        atomicAdd(&cnt[((unsigned)words[e]) >> 24], 1);
    __syncthreads();
    int node = b * S + t;
    if (node < n) {
        float di = rsqrtf((float)(cnt[t] + 1));    // +1 self-loop
        dinv[node] = di;
        float4 xv = reinterpret_cast<const float4*>(x)[node];
        float4 o = { xv.x * di, xv.y * di, xv.z * di, xv.w * di };
        reinterpret_cast<float4*>(xd)[node] = o;
    }
}

// ---- layer-1: bucket-local LDS aggregation + fused 4->16(relu)->4 MLP ----
// agg layout agg[k*S + dl]: bank = dl%32 -> ~2-way conflicts (free)
__global__ void __launch_bounds__(BLK) k_agg1(const int* __restrict__ words,
                                              const int* __restrict__ offs,
                                              const float* __restrict__ dinv,
                                              const float* __restrict__ xd,
                                              const float* __restrict__ W1,
                                              const float* __restrict__ b1,
                                              const float* __restrict__ W2,
                                              float* __restrict__ g2,
                                              int n, int E, int NB) {
    __shared__ float agg[4 * S];
    int b = blockIdx.x, t = threadIdx.x;
    agg[t] = 0.f; agg[S + t] = 0.f; agg[2 * S + t] = 0.f; agg[3 * S + t] = 0.f;
    __syncthreads();
    int e0 = offs[b * G];
    int e1 = (b + 1 < NB) ? offs[(b + 1) * G] : E;
    for (int e = e0 + t; e < e1; e += BLK) {
        unsigned w = (unsigned)words[e];
        int s  = w & 0xFFFFFF;
        int dl = w >> 24;
        float4 v = reinterpret_cast<const float4*>(xd)[s];  // L2-resident gather
        atomicAdd(&agg[dl],         v.x);
        atomicAdd(&agg[S + dl],     v.y);
        atomicAdd(&agg[2 * S + dl], v.z);
        atomicAdd(&agg[3 * S + dl], v.w);
    }
    __syncthreads();
    int node = b * S + t;
    if (node >= n) return;
    float di = dinv[node];
    float4 xv = reinterpret_cast<const float4*>(xd)[node];  // self-loop term
    float sx = agg[t] + xv.x, sy = agg[S + t] + xv.y;
    float sz = agg[2 * S + t] + xv.z, sw = agg[3 * S + t] + xv.w;
    float o0 = 0.f, o1 = 0.f, o2 = 0.f, o3 = 0.f;
#pragma unroll
    for (int j = 0; j < 16; ++j) {
        // W1 [4][16] row-major; wave-uniform index -> scalar broadcast
        float h = sx * W1[j] + sy * W1[16 + j] + sz * W1[32 + j] + sw * W1[48 + j];
        float v = di * h + b1[j];
        v = v > 0.f ? v : 0.f;   // relu
        o0 += v * W2[j * 4 + 0];
        o1 += v * W2[j * 4 + 1];
        o2 += v * W2[j * 4 + 2];
        o3 += v * W2[j * 4 + 3];
    }
    float4 o = { o0 * di, o1 * di, o2 * di, o3 * di };
    reinterpret_cast<float4*>(g2)[node] = o;
}

// ---- layer-2: bucket-local LDS aggregation + bias + log_softmax ----
__global__ void __launch_bounds__(BLK) k_agg2(const int* __restrict__ words,
                                              const int* __restrict__ offs,
                                              const float* __restrict__ dinv,
                                              const float* __restrict__ g2,
                                              const float* __restrict__ b2,
                                              float* __restrict__ out,
                                              int n, int E, int NB) {
    __shared__ float agg[4 * S];
    int b = blockIdx.x, t = threadIdx.x;
    agg[t] = 0.f; agg[S + t] = 0.f; agg[2 * S + t] = 0.f; agg[3 * S + t] = 0.f;
    __syncthreads();
    int e0 = offs[b * G];
    int e1 = (b + 1 < NB) ? offs[(b + 1) * G] : E;
    for (int e = e0 + t; e < e1; e += BLK) {
        unsigned w = (unsigned)words[e];
        int s  = w & 0xFFFFFF;
        int dl = w >> 24;
        float4 v = reinterpret_cast<const float4*>(g2)[s];
        atomicAdd(&agg[dl],         v.x);
        atomicAdd(&agg[S + dl],     v.y);
        atomicAdd(&agg[2 * S + dl], v.z);
        atomicAdd(&agg[3 * S + dl], v.w);
    }
    __syncthreads();
    int node = b * S + t;
    if (node >= n) return;
    float di = dinv[node];
    float4 gv = reinterpret_cast<const float4*>(g2)[node];  // self-loop term
    float o0 = di * (agg[t]         + gv.x) + b2[0];
    float o1 = di * (agg[S + t]     + gv.y) + b2[1];
    float o2 = di * (agg[2 * S + t] + gv.z) + b2[2];
    float o3 = di * (agg[3 * S + t] + gv.w) + b2[3];
    float m = fmaxf(fmaxf(o0, o1), fmaxf(o2, o3));
    float sm = expf(o0 - m) + expf(o1 - m) + expf(o2 - m) + expf(o3 - m);
    float l = m + logf(sm);
    float4 r = { o0 - l, o1 - l, o2 - l, o3 - l };
    reinterpret_cast<float4*>(out)[node] = r;
}

extern "C" void kernel_launch(void* const* d_in, const int* in_sizes, int n_in,
                              void* d_out, int out_size, void* d_ws, size_t ws_size,
                              hipStream_t stream) {
    const float* x  = (const float*)d_in[0];
    const float* W1 = (const float*)d_in[1];
    const float* b1 = (const float*)d_in[2];
    const float* W2 = (const float*)d_in[3];
    const float* b2 = (const float*)d_in[4];
    const int*   ei = (const int*)d_in[5];

    const int n = in_sizes[0] / 4;   // 100000
    const int E = in_sizes[5] / 2;   // 3200000
    const int* src = ei;
    const int* dst = ei + E;

    const int NB    = (n + S - 1) / S;        // 391 buckets
    const int chunk = (E + G - 1) / G;        // 12500 edges/chunk
    const int m     = NB * G;                 // 100096 scan elements
    const int mB    = (m + BLK - 1) / BLK;    // 391 scan blocks

    // workspace (16B-aligned; ~16.7 MB; every used byte rewritten each call)
    char* ws = (char*)d_ws;
    size_t off = 0;
    int*   words = (int*)  (ws + off); off += (size_t)E * 4;     // 12.8 MB
    int*   offs  = (int*)  (ws + off); off += (size_t)m * 4;     // 400 KB (hist -> scan in place)
    float* xd    = (float*)(ws + off); off += (size_t)n * 16;    // 1.6 MB
    float* g2    = (float*)(ws + off); off += (size_t)n * 16;    // 1.6 MB
    float* dinv  = (float*)(ws + off); off += (size_t)n * 4;     // 400 KB
    int*   bsum  = (int*)  (ws + off); off += 1024 * 4;
    int*   boff  = (int*)  (ws + off); off += 1024 * 4;
    float* out   = (float*)d_out;

    k_binA <<<G,  BLK,  0, stream>>>(dst, offs, E, NB, chunk);
    k_scanA<<<mB, BLK,  0, stream>>>(offs, bsum, m);
    k_scanB<<<1,  1024, 0, stream>>>(bsum, boff, mB);
    k_scanC<<<mB, BLK,  0, stream>>>(offs, boff, m);
    k_binB <<<G,  BLK,  0, stream>>>(src, dst, offs, words, E, NB, chunk);
    k_bdeg <<<NB, BLK,  0, stream>>>(words, offs, x, dinv, xd, n, E, NB);
    k_agg1 <<<NB, BLK,  0, stream>>>(words, offs, dinv, xd, W1, b1, W2, g2, n, E, NB);
    k_agg2 <<<NB, BLK,  0, stream>>>(words, offs, dinv, g2, b2, out, n, E, NB);
}

// Round 8
// 291.289 us; speedup vs baseline: 11.9361x; 1.1157x over previous
//
#include <hip/hip_runtime.h>
#include <math.h>

// GCN 2-layer forward, zero global atomics, occupancy-fixed.
// Round-7: agg kernels ran at 12% occupancy (391 blocks on 256 CUs), 1% VALU,
// 2% HBM -> pure latency-bound. Fix: K-way split of every per-bucket edge
// stream (grid NB*K = 3128) with coalesced partial writes + per-bucket
// combine kernels. Binning G=512 chunks.
//
//   out = log_softmax( Dinv(A+I)Dinv' relu( Dinv(A+I)Dinv' X W1 + b1 ) W2 + b2 )
// Aggregation commutes with W1 -> both layers aggregate 4-vectors.

#define BLK   256
#define G     512      // binning chunks
#define SH    8        // log2(nodes per bucket)
#define S     256      // nodes per bucket
#define MAXNB 512      // LDS bucket-table capacity (NB = 391)

// ---- pass A: per-chunk bucket histogram (LDS atomics only) ----
__global__ void __launch_bounds__(BLK) k_binA(const int* __restrict__ dst,
                                              int* __restrict__ gh,
                                              int E, int NB, int chunk) {
    __shared__ int hist[MAXNB];
    int g = blockIdx.x, t = threadIdx.x;
    for (int j = t; j < NB; j += BLK) hist[j] = 0;
    __syncthreads();
    int e0 = g * chunk, e1 = min(e0 + chunk, E);
    for (int e = e0 + t; e < e1; e += BLK)
        atomicAdd(&hist[dst[e] >> SH], 1);
    __syncthreads();
    for (int j = t; j < NB; j += BLK) gh[j * G + g] = hist[j];  // [bucket][chunk]
}

// ---- 3-kernel exclusive scan over m = NB*G elements (in place) ----
__global__ void __launch_bounds__(BLK) k_scanA(const int* __restrict__ a,
                                               int* __restrict__ bsum, int m) {
    __shared__ int sh[BLK];
    int i = blockIdx.x * BLK + threadIdx.x;
    sh[threadIdx.x] = (i < m) ? a[i] : 0;
    __syncthreads();
    for (int off = BLK >> 1; off > 0; off >>= 1) {
        if (threadIdx.x < off) sh[threadIdx.x] += sh[threadIdx.x + off];
        __syncthreads();
    }
    if (threadIdx.x == 0) bsum[blockIdx.x] = sh[0];
}

__global__ void __launch_bounds__(1024) k_scanB(const int* __restrict__ bsum,
                                                int* __restrict__ boff, int nb) {
    __shared__ int sh[1024];
    int t = threadIdx.x;
    int v = (t < nb) ? bsum[t] : 0;
    sh[t] = v; __syncthreads();
    for (int off = 1; off < 1024; off <<= 1) {
        int u = (t >= off) ? sh[t - off] : 0;
        __syncthreads();
        sh[t] += u;
        __syncthreads();
    }
    if (t < nb) boff[t] = sh[t] - v;   // exclusive
}

__global__ void __launch_bounds__(BLK) k_scanC(int* __restrict__ a,
                                               const int* __restrict__ boff, int m) {
    __shared__ int sh[BLK];
    int t = threadIdx.x;
    int i = blockIdx.x * BLK + t;
    int v = (i < m) ? a[i] : 0;
    sh[t] = v; __syncthreads();
    for (int off = 1; off < BLK; off <<= 1) {
        int u = (t >= off) ? sh[t - off] : 0;
        __syncthreads();
        sh[t] += u;
        __syncthreads();
    }
    if (i < m) a[i] = sh[t] - v + boff[blockIdx.x];
}

// ---- pass B: scatter packed edges into bucket-contiguous runs ----
// word = src | (dst&255)<<24   (src < 2^24)
__global__ void __launch_bounds__(BLK) k_binB(const int* __restrict__ src,
                                              const int* __restrict__ dst,
                                              const int* __restrict__ offs,
                                              int* __restrict__ words,
                                              int E, int NB, int chunk) {
    __shared__ int cur[MAXNB];
    int g = blockIdx.x, t = threadIdx.x;
    for (int j = t; j < NB; j += BLK) cur[j] = offs[j * G + g];
    __syncthreads();
    int e0 = g * chunk, e1 = min(e0 + chunk, E);
    for (int e = e0 + t; e < e1; e += BLK) {
        int d = dst[e];
        int b = d >> SH;
        int pos = atomicAdd(&cur[b], 1);           // LDS atomic
        words[pos] = src[e] | ((d & (S - 1)) << 24);
    }
}

// ---- degree: K-way split per bucket, LDS count, coalesced partial write ----
__global__ void __launch_bounds__(BLK) k_cnt_split(const int* __restrict__ words,
                                                   const int* __restrict__ offs,
                                                   int* __restrict__ pcnt,
                                                   int E, int NB, int K) {
    __shared__ int cnt[S];
    int b = blockIdx.x / K, k = blockIdx.x % K, t = threadIdx.x;
    cnt[t] = 0;
    __syncthreads();
    int e0 = offs[b * G];
    int e1 = (b + 1 < NB) ? offs[(b + 1) * G] : E;
    long len = e1 - e0;
    int es = e0 + (int)(len * k / K);
    int ee = e0 + (int)(len * (k + 1) / K);
    for (int e = es + t; e < ee; e += BLK)
        atomicAdd(&cnt[((unsigned)words[e]) >> 24], 1);
    __syncthreads();
    pcnt[(b * K + k) * S + t] = cnt[t];            // coalesced
}

// ---- combine degree partials; dinv = rsqrt(deg+1); xd = x*dinv ----
__global__ void __launch_bounds__(BLK) k_cnt_comb(const int* __restrict__ pcnt,
                                                  const float* __restrict__ x,
                                                  float* __restrict__ dinv,
                                                  float* __restrict__ xd,
                                                  int n, int K) {
    int b = blockIdx.x, t = threadIdx.x;
    int node = b * S + t;
    if (node >= n) return;
    int c = 0;
    for (int k = 0; k < K; ++k) c += pcnt[(b * K + k) * S + t];
    float di = rsqrtf((float)(c + 1));             // +1 self-loop
    dinv[node] = di;
    float4 xv = reinterpret_cast<const float4*>(x)[node];
    float4 o = { xv.x * di, xv.y * di, xv.z * di, xv.w * di };
    reinterpret_cast<float4*>(xd)[node] = o;
}

// ---- aggregation split: LDS f32 atomics, coalesced float4 partial write ----
// agg[c*S+dl]: per-instruction banks = dl%32 (random ~2-way, free)
__global__ void __launch_bounds__(BLK) k_agg_split(const int* __restrict__ words,
                                                   const int* __restrict__ offs,
                                                   const float* __restrict__ feat,
                                                   float4* __restrict__ pagg,
                                                   int E, int NB, int K) {
    __shared__ float agg[4 * S];
    int b = blockIdx.x / K, k = blockIdx.x % K, t = threadIdx.x;
    agg[t] = 0.f; agg[S + t] = 0.f; agg[2 * S + t] = 0.f; agg[3 * S + t] = 0.f;
    __syncthreads();
    int e0 = offs[b * G];
    int e1 = (b + 1 < NB) ? offs[(b + 1) * G] : E;
    long len = e1 - e0;
    int es = e0 + (int)(len * k / K);
    int ee = e0 + (int)(len * (k + 1) / K);
    for (int e = es + t; e < ee; e += BLK) {
        unsigned w = (unsigned)words[e];
        int s  = w & 0xFFFFFF;
        int dl = w >> 24;
        float4 v = reinterpret_cast<const float4*>(feat)[s];  // L2-resident gather
        atomicAdd(&agg[dl],         v.x);
        atomicAdd(&agg[S + dl],     v.y);
        atomicAdd(&agg[2 * S + dl], v.z);
        atomicAdd(&agg[3 * S + dl], v.w);
    }
    __syncthreads();
    float4 p = { agg[t], agg[S + t], agg[2 * S + t], agg[3 * S + t] };
    pagg[(b * K + k) * S + t] = p;                 // coalesced
}

// ---- layer-1 combine: sum partials + self + fused 4->16(relu)->4 MLP ----
__global__ void __launch_bounds__(BLK) k_comb1(const float4* __restrict__ pagg,
                                               const float* __restrict__ dinv,
                                               const float* __restrict__ xd,
                                               const float* __restrict__ W1,
                                               const float* __restrict__ b1,
                                               const float* __restrict__ W2,
                                               float* __restrict__ g2,
                                               int n, int K) {
    int b = blockIdx.x, t = threadIdx.x;
    int node = b * S + t;
    if (node >= n) return;
    float4 s = reinterpret_cast<const float4*>(xd)[node];   // self-loop term
    for (int k = 0; k < K; ++k) {
        float4 p = pagg[(b * K + k) * S + t];
        s.x += p.x; s.y += p.y; s.z += p.z; s.w += p.w;
    }
    float di = dinv[node];
    float o0 = 0.f, o1 = 0.f, o2 = 0.f, o3 = 0.f;
#pragma unroll
    for (int j = 0; j < 16; ++j) {
        // W1 [4][16] row-major; wave-uniform -> scalar broadcast
        float h = s.x * W1[j] + s.y * W1[16 + j] + s.z * W1[32 + j] + s.w * W1[48 + j];
        float v = di * h + b1[j];
        v = v > 0.f ? v : 0.f;   // relu
        o0 += v * W2[j * 4 + 0];
        o1 += v * W2[j * 4 + 1];
        o2 += v * W2[j * 4 + 2];
        o3 += v * W2[j * 4 + 3];
    }
    float4 o = { o0 * di, o1 * di, o2 * di, o3 * di };
    reinterpret_cast<float4*>(g2)[node] = o;
}

// ---- layer-2 combine: sum partials + self + bias + log_softmax ----
__global__ void __launch_bounds__(BLK) k_comb2(const float4* __restrict__ pagg,
                                               const float* __restrict__ dinv,
                                               const float* __restrict__ g2,
                                               const float* __restrict__ b2,
                                               float* __restrict__ out,
                                               int n, int K) {
    int b = blockIdx.x, t = threadIdx.x;
    int node = b * S + t;
    if (node >= n) return;
    float4 s = reinterpret_cast<const float4*>(g2)[node];   // self-loop term
    for (int k = 0; k < K; ++k) {
        float4 p = pagg[(b * K + k) * S + t];
        s.x += p.x; s.y += p.y; s.z += p.z; s.w += p.w;
    }
    float di = dinv[node];
    float o0 = di * s.x + b2[0];
    float o1 = di * s.y + b2[1];
    float o2 = di * s.z + b2[2];
    float o3 = di * s.w + b2[3];
    float m = fmaxf(fmaxf(o0, o1), fmaxf(o2, o3));
    float sm = expf(o0 - m) + expf(o1 - m) + expf(o2 - m) + expf(o3 - m);
    float l = m + logf(sm);
    float4 r = { o0 - l, o1 - l, o2 - l, o3 - l };
    reinterpret_cast<float4*>(out)[node] = r;
}

extern "C" void kernel_launch(void* const* d_in, const int* in_sizes, int n_in,
                              void* d_out, int out_size, void* d_ws, size_t ws_size,
                              hipStream_t stream) {
    const float* x  = (const float*)d_in[0];
    const float* W1 = (const float*)d_in[1];
    const float* b1 = (const float*)d_in[2];
    const float* W2 = (const float*)d_in[3];
    const float* b2 = (const float*)d_in[4];
    const int*   ei = (const int*)d_in[5];

    const int n = in_sizes[0] / 4;   // 100000
    const int E = in_sizes[5] / 2;   // 3200000
    const int* src = ei;
    const int* dst = ei + E;

    const int NB    = (n + S - 1) / S;        // 391 buckets
    const int chunk = (E + G - 1) / G;        // 6250 edges/chunk
    const int m     = NB * G;                 // 200192 scan elements
    const int mB    = (m + BLK - 1) / BLK;    // 782 (<= 1024 for scanB)

    // workspace layout (16B-aligned)
    char* ws = (char*)d_ws;
    size_t off = 0;
    int*    words = (int*)   (ws + off); off += (size_t)E * 4;    // 12.8 MB
    int*    offs  = (int*)   (ws + off); off += (size_t)m * 4;    // 800 KB
    float*  xd    = (float*) (ws + off); off += (size_t)n * 16;   // 1.6 MB
    float*  g2    = (float*) (ws + off); off += (size_t)n * 16;   // 1.6 MB
    float*  dinv  = (float*) (ws + off); off += (size_t)n * 4;    // 400 KB
    int*    bsum  = (int*)   (ws + off); off += 4096;
    int*    boff  = (int*)   (ws + off); off += 4096;
    // partial buffer: f32x4 partials for agg; int partials for degree alias it
    float4* pagg  = (float4*)(ws + off);
    int*    pcnt  = (int*)   (ws + off);
    size_t base = off;
    int K = 8;
    while (K > 1 && base + (size_t)NB * K * S * 16 > ws_size) K >>= 1;
    float* out = (float*)d_out;

    k_binA     <<<G,      BLK,  0, stream>>>(dst, offs, E, NB, chunk);
    k_scanA    <<<mB,     BLK,  0, stream>>>(offs, bsum, m);
    k_scanB    <<<1,      1024, 0, stream>>>(bsum, boff, mB);
    k_scanC    <<<mB,     BLK,  0, stream>>>(offs, boff, m);
    k_binB     <<<G,      BLK,  0, stream>>>(src, dst, offs, words, E, NB, chunk);
    k_cnt_split<<<NB * K, BLK,  0, stream>>>(words, offs, pcnt, E, NB, K);
    k_cnt_comb <<<NB,     BLK,  0, stream>>>(pcnt, x, dinv, xd, n, K);
    k_agg_split<<<NB * K, BLK,  0, stream>>>(words, offs, xd, pagg, E, NB, K);
    k_comb1    <<<NB,     BLK,  0, stream>>>(pagg, dinv, xd, W1, b1, W2, g2, n, K);
    k_agg_split<<<NB * K, BLK,  0, stream>>>(words, offs, g2, pagg, E, NB, K);
    k_comb2    <<<NB,     BLK,  0, stream>>>(pagg, dinv, g2, b2, out, n, K);
}

// Round 9
// 281.039 us; speedup vs baseline: 12.3714x; 1.0365x over previous
//
#include <hip/hip_runtime.h>
#include <math.h>

// GCN 2-layer forward, zero global atomics, ILP-batched.
// Round-8: agg_split at 59% occupancy still 74us (VALU 1.3%, HBM 4.4%) ->
// per-thread serial dependent chains (scalar word load -> gather -> atomics,
// only 4 iters) eat full HBM/L2 latency. Fix: int4-batch 4 edges/thread,
// issue 4 independent gathers together (4x MLP), same for cnt/binA/binB.
//
//   out = log_softmax( Dinv(A+I)Dinv' relu( Dinv(A+I)Dinv' X W1 + b1 ) W2 + b2 )
// Aggregation commutes with W1 -> both layers aggregate 4-vectors.

#define BLK   256
#define G     512      // binning chunks
#define SH    8        // log2(nodes per bucket)
#define S     256      // nodes per bucket
#define MAXNB 512      // LDS bucket-table capacity (NB = 391)

// ---- pass A: per-chunk bucket histogram (LDS atomics, int4-batched) ----
__global__ void __launch_bounds__(BLK) k_binA(const int* __restrict__ dst,
                                              int* __restrict__ gh,
                                              int E, int NB, int chunk) {
    __shared__ int hist[MAXNB];
    int g = blockIdx.x, t = threadIdx.x;
    for (int j = t; j < NB; j += BLK) hist[j] = 0;
    __syncthreads();
    int bs = g * chunk, be = min(bs + chunk, E);
    int bs4 = (bs + 3) & ~3, be4 = be & ~3;
    if (be4 <= bs4) {
        for (int e = bs + t; e < be; e += BLK)
            atomicAdd(&hist[dst[e] >> SH], 1);
    } else {
        if (t < bs4 - bs) atomicAdd(&hist[dst[bs + t] >> SH], 1);
        for (int e = bs4 + 4 * t; e < be4; e += 4 * BLK) {
            int4 d = *reinterpret_cast<const int4*>(dst + e);
            atomicAdd(&hist[d.x >> SH], 1);
            atomicAdd(&hist[d.y >> SH], 1);
            atomicAdd(&hist[d.z >> SH], 1);
            atomicAdd(&hist[d.w >> SH], 1);
        }
        if (t < be - be4) atomicAdd(&hist[dst[be4 + t] >> SH], 1);
    }
    __syncthreads();
    for (int j = t; j < NB; j += BLK) gh[j * G + g] = hist[j];  // [bucket][chunk]
}

// ---- 3-kernel exclusive scan over m = NB*G elements (in place) ----
__global__ void __launch_bounds__(BLK) k_scanA(const int* __restrict__ a,
                                               int* __restrict__ bsum, int m) {
    __shared__ int sh[BLK];
    int i = blockIdx.x * BLK + threadIdx.x;
    sh[threadIdx.x] = (i < m) ? a[i] : 0;
    __syncthreads();
    for (int off = BLK >> 1; off > 0; off >>= 1) {
        if (threadIdx.x < off) sh[threadIdx.x] += sh[threadIdx.x + off];
        __syncthreads();
    }
    if (threadIdx.x == 0) bsum[blockIdx.x] = sh[0];
}

__global__ void __launch_bounds__(1024) k_scanB(const int* __restrict__ bsum,
                                                int* __restrict__ boff, int nb) {
    __shared__ int sh[1024];
    int t = threadIdx.x;
    int v = (t < nb) ? bsum[t] : 0;
    sh[t] = v; __syncthreads();
    for (int off = 1; off < 1024; off <<= 1) {
        int u = (t >= off) ? sh[t - off] : 0;
        __syncthreads();
        sh[t] += u;
        __syncthreads();
    }
    if (t < nb) boff[t] = sh[t] - v;   // exclusive
}

__global__ void __launch_bounds__(BLK) k_scanC(int* __restrict__ a,
                                               const int* __restrict__ boff, int m) {
    __shared__ int sh[BLK];
    int t = threadIdx.x;
    int i = blockIdx.x * BLK + t;
    int v = (i < m) ? a[i] : 0;
    sh[t] = v; __syncthreads();
    for (int off = 1; off < BLK; off <<= 1) {
        int u = (t >= off) ? sh[t - off] : 0;
        __syncthreads();
        sh[t] += u;
        __syncthreads();
    }
    if (i < m) a[i] = sh[t] - v + boff[blockIdx.x];
}

// ---- pass B: scatter packed edges into bucket-contiguous runs ----
// word = src | (dst&255)<<24   (src < 2^24)
__global__ void __launch_bounds__(BLK) k_binB(const int* __restrict__ src,
                                              const int* __restrict__ dst,
                                              const int* __restrict__ offs,
                                              int* __restrict__ words,
                                              int E, int NB, int chunk) {
    __shared__ int cur[MAXNB];
    int g = blockIdx.x, t = threadIdx.x;
    for (int j = t; j < NB; j += BLK) cur[j] = offs[j * G + g];
    __syncthreads();
    int bs = g * chunk, be = min(bs + chunk, E);
    int bs4 = (bs + 3) & ~3, be4 = be & ~3;
    if (be4 <= bs4) {
        for (int e = bs + t; e < be; e += BLK) {
            int d = dst[e];
            int pos = atomicAdd(&cur[d >> SH], 1);
            words[pos] = src[e] | ((d & (S - 1)) << 24);
        }
    } else {
        if (t < bs4 - bs) {
            int e = bs + t, d = dst[e];
            int pos = atomicAdd(&cur[d >> SH], 1);
            words[pos] = src[e] | ((d & (S - 1)) << 24);
        }
        for (int e = bs4 + 4 * t; e < be4; e += 4 * BLK) {
            int4 d = *reinterpret_cast<const int4*>(dst + e);
            int4 s = *reinterpret_cast<const int4*>(src + e);
            int p0 = atomicAdd(&cur[d.x >> SH], 1);
            int p1 = atomicAdd(&cur[d.y >> SH], 1);
            int p2 = atomicAdd(&cur[d.z >> SH], 1);
            int p3 = atomicAdd(&cur[d.w >> SH], 1);
            words[p0] = s.x | ((d.x & (S - 1)) << 24);
            words[p1] = s.y | ((d.y & (S - 1)) << 24);
            words[p2] = s.z | ((d.z & (S - 1)) << 24);
            words[p3] = s.w | ((d.w & (S - 1)) << 24);
        }
        if (t < be - be4) {
            int e = be4 + t, d = dst[e];
            int pos = atomicAdd(&cur[d >> SH], 1);
            words[pos] = src[e] | ((d & (S - 1)) << 24);
        }
    }
}

// ---- degree: K-way split per bucket, LDS count (int4-batched) ----
__global__ void __launch_bounds__(BLK) k_cnt_split(const int* __restrict__ words,
                                                   const int* __restrict__ offs,
                                                   int* __restrict__ pcnt,
                                                   int E, int NB, int K) {
    __shared__ int cnt[S];
    int b = blockIdx.x / K, k = blockIdx.x % K, t = threadIdx.x;
    cnt[t] = 0;
    __syncthreads();
    int e0 = offs[b * G];
    int e1 = (b + 1 < NB) ? offs[(b + 1) * G] : E;
    long len = e1 - e0;
    int bs = e0 + (int)(len * k / K);
    int be = e0 + (int)(len * (k + 1) / K);
    int bs4 = (bs + 3) & ~3, be4 = be & ~3;
    if (be4 <= bs4) {
        for (int e = bs + t; e < be; e += BLK)
            atomicAdd(&cnt[((unsigned)words[e]) >> 24], 1);
    } else {
        if (t < bs4 - bs) atomicAdd(&cnt[((unsigned)words[bs + t]) >> 24], 1);
        for (int e = bs4 + 4 * t; e < be4; e += 4 * BLK) {
            int4 w = *reinterpret_cast<const int4*>(words + e);
            atomicAdd(&cnt[((unsigned)w.x) >> 24], 1);
            atomicAdd(&cnt[((unsigned)w.y) >> 24], 1);
            atomicAdd(&cnt[((unsigned)w.z) >> 24], 1);
            atomicAdd(&cnt[((unsigned)w.w) >> 24], 1);
        }
        if (t < be - be4) atomicAdd(&cnt[((unsigned)words[be4 + t]) >> 24], 1);
    }
    __syncthreads();
    pcnt[(b * K + k) * S + t] = cnt[t];            // coalesced
}

// ---- combine degree partials; dinv = rsqrt(deg+1); xd = x*dinv ----
__global__ void __launch_bounds__(BLK) k_cnt_comb(const int* __restrict__ pcnt,
                                                  const float* __restrict__ x,
                                                  float* __restrict__ dinv,
                                                  float* __restrict__ xd,
                                                  int n, int K) {
    int b = blockIdx.x, t = threadIdx.x;
    int node = b * S + t;
    if (node >= n) return;
    int c = 0;
    for (int k = 0; k < K; ++k) c += pcnt[(b * K + k) * S + t];
    float di = rsqrtf((float)(c + 1));             // +1 self-loop
    dinv[node] = di;
    float4 xv = reinterpret_cast<const float4*>(x)[node];
    float4 o = { xv.x * di, xv.y * di, xv.z * di, xv.w * di };
    reinterpret_cast<float4*>(xd)[node] = o;
}

// ---- aggregation split: int4 word batch + 4 independent gathers + LDS f32 ----
__device__ __forceinline__ void agg_one(float* agg, unsigned w, const float4* feat4) {
    int s  = w & 0xFFFFFF;
    int dl = w >> 24;
    float4 v = feat4[s];
    atomicAdd(&agg[dl],         v.x);
    atomicAdd(&agg[S + dl],     v.y);
    atomicAdd(&agg[2 * S + dl], v.z);
    atomicAdd(&agg[3 * S + dl], v.w);
}

__global__ void __launch_bounds__(BLK) k_agg_split(const int* __restrict__ words,
                                                   const int* __restrict__ offs,
                                                   const float* __restrict__ feat,
                                                   float4* __restrict__ pagg,
                                                   int E, int NB, int K) {
    __shared__ float agg[4 * S];
    int b = blockIdx.x / K, k = blockIdx.x % K, t = threadIdx.x;
    agg[t] = 0.f; agg[S + t] = 0.f; agg[2 * S + t] = 0.f; agg[3 * S + t] = 0.f;
    __syncthreads();
    const float4* feat4 = reinterpret_cast<const float4*>(feat);
    int e0 = offs[b * G];
    int e1 = (b + 1 < NB) ? offs[(b + 1) * G] : E;
    long len = e1 - e0;
    int bs = e0 + (int)(len * k / K);
    int be = e0 + (int)(len * (k + 1) / K);
    int bs4 = (bs + 3) & ~3, be4 = be & ~3;
    if (be4 <= bs4) {
        for (int e = bs + t; e < be; e += BLK)
            agg_one(agg, (unsigned)words[e], feat4);
    } else {
        if (t < bs4 - bs) agg_one(agg, (unsigned)words[bs + t], feat4);
        for (int e = bs4 + 4 * t; e < be4; e += 4 * BLK) {
            int4 wv = *reinterpret_cast<const int4*>(words + e);
            unsigned w0 = wv.x, w1 = wv.y, w2 = wv.z, w3 = wv.w;
            // 4 independent gathers issue back-to-back (4x MLP)
            float4 v0 = feat4[w0 & 0xFFFFFF];
            float4 v1 = feat4[w1 & 0xFFFFFF];
            float4 v2 = feat4[w2 & 0xFFFFFF];
            float4 v3 = feat4[w3 & 0xFFFFFF];
            int d0 = w0 >> 24, d1 = w1 >> 24, d2 = w2 >> 24, d3 = w3 >> 24;
            atomicAdd(&agg[d0], v0.x);         atomicAdd(&agg[S + d0], v0.y);
            atomicAdd(&agg[2 * S + d0], v0.z); atomicAdd(&agg[3 * S + d0], v0.w);
            atomicAdd(&agg[d1], v1.x);         atomicAdd(&agg[S + d1], v1.y);
            atomicAdd(&agg[2 * S + d1], v1.z); atomicAdd(&agg[3 * S + d1], v1.w);
            atomicAdd(&agg[d2], v2.x);         atomicAdd(&agg[S + d2], v2.y);
            atomicAdd(&agg[2 * S + d2], v2.z); atomicAdd(&agg[3 * S + d2], v2.w);
            atomicAdd(&agg[d3], v3.x);         atomicAdd(&agg[S + d3], v3.y);
            atomicAdd(&agg[2 * S + d3], v3.z); atomicAdd(&agg[3 * S + d3], v3.w);
        }
        if (t < be - be4) agg_one(agg, (unsigned)words[be4 + t], feat4);
    }
    __syncthreads();
    float4 p = { agg[t], agg[S + t], agg[2 * S + t], agg[3 * S + t] };
    pagg[(b * K + k) * S + t] = p;                 // coalesced
}

// ---- layer-1 combine: sum partials + self + fused 4->16(relu)->4 MLP ----
__global__ void __launch_bounds__(BLK) k_comb1(const float4* __restrict__ pagg,
                                               const float* __restrict__ dinv,
                                               const float* __restrict__ xd,
                                               const float* __restrict__ W1,
                                               const float* __restrict__ b1,
                                               const float* __restrict__ W2,
                                               float* __restrict__ g2,
                                               int n, int K) {
    int b = blockIdx.x, t = threadIdx.x;
    int node = b * S + t;
    if (node >= n) return;
    float4 s = reinterpret_cast<const float4*>(xd)[node];   // self-loop term
    for (int k = 0; k < K; ++k) {
        float4 p = pagg[(b * K + k) * S + t];
        s.x += p.x; s.y += p.y; s.z += p.z; s.w += p.w;
    }
    float di = dinv[node];
    float o0 = 0.f, o1 = 0.f, o2 = 0.f, o3 = 0.f;
#pragma unroll
    for (int j = 0; j < 16; ++j) {
        // W1 [4][16] row-major; wave-uniform -> scalar broadcast
        float h = s.x * W1[j] + s.y * W1[16 + j] + s.z * W1[32 + j] + s.w * W1[48 + j];
        float v = di * h + b1[j];
        v = v > 0.f ? v : 0.f;   // relu
        o0 += v * W2[j * 4 + 0];
        o1 += v * W2[j * 4 + 1];
        o2 += v * W2[j * 4 + 2];
        o3 += v * W2[j * 4 + 3];
    }
    float4 o = { o0 * di, o1 * di, o2 * di, o3 * di };
    reinterpret_cast<float4*>(g2)[node] = o;
}

// ---- layer-2 combine: sum partials + self + bias + log_softmax ----
__global__ void __launch_bounds__(BLK) k_comb2(const float4* __restrict__ pagg,
                                               const float* __restrict__ dinv,
                                               const float* __restrict__ g2,
                                               const float* __restrict__ b2,
                                               float* __restrict__ out,
                                               int n, int K) {
    int b = blockIdx.x, t = threadIdx.x;
    int node = b * S + t;
    if (node >= n) return;
    float4 s = reinterpret_cast<const float4*>(g2)[node];   // self-loop term
    for (int k = 0; k < K; ++k) {
        float4 p = pagg[(b * K + k) * S + t];
        s.x += p.x; s.y += p.y; s.z += p.z; s.w += p.w;
    }
    float di = dinv[node];
    float o0 = di * s.x + b2[0];
    float o1 = di * s.y + b2[1];
    float o2 = di * s.z + b2[2];
    float o3 = di * s.w + b2[3];
    float m = fmaxf(fmaxf(o0, o1), fmaxf(o2, o3));
    float sm = expf(o0 - m) + expf(o1 - m) + expf(o2 - m) + expf(o3 - m);
    float l = m + logf(sm);
    float4 r = { o0 - l, o1 - l, o2 - l, o3 - l };
    reinterpret_cast<float4*>(out)[node] = r;
}

extern "C" void kernel_launch(void* const* d_in, const int* in_sizes, int n_in,
                              void* d_out, int out_size, void* d_ws, size_t ws_size,
                              hipStream_t stream) {
    const float* x  = (const float*)d_in[0];
    const float* W1 = (const float*)d_in[1];
    const float* b1 = (const float*)d_in[2];
    const float* W2 = (const float*)d_in[3];
    const float* b2 = (const float*)d_in[4];
    const int*   ei = (const int*)d_in[5];

    const int n = in_sizes[0] / 4;   // 100000
    const int E = in_sizes[5] / 2;   // 3200000
    const int* src = ei;
    const int* dst = ei + E;

    const int NB    = (n + S - 1) / S;        // 391 buckets
    const int chunk = (E + G - 1) / G;        // 6250 edges/chunk
    const int m     = NB * G;                 // 200192 scan elements
    const int mB    = (m + BLK - 1) / BLK;    // 782 (<= 1024 for scanB)

    // workspace layout (16B-aligned)
    char* ws = (char*)d_ws;
    size_t off = 0;
    int*    words = (int*)   (ws + off); off += (size_t)E * 4;    // 12.8 MB
    int*    offs  = (int*)   (ws + off); off += (size_t)m * 4;    // 800 KB
    float*  xd    = (float*) (ws + off); off += (size_t)n * 16;   // 1.6 MB
    float*  g2    = (float*) (ws + off); off += (size_t)n * 16;   // 1.6 MB
    float*  dinv  = (float*) (ws + off); off += (size_t)n * 4;    // 400 KB
    int*    bsum  = (int*)   (ws + off); off += 4096;
    int*    boff  = (int*)   (ws + off); off += 4096;
    // partial buffer: f32x4 partials for agg; int partials for degree alias it
    float4* pagg  = (float4*)(ws + off);
    int*    pcnt  = (int*)   (ws + off);
    size_t base = off;
    int K = 8;
    while (K > 1 && base + (size_t)NB * K * S * 16 > ws_size) K >>= 1;
    float* out = (float*)d_out;

    k_binA     <<<G,      BLK,  0, stream>>>(dst, offs, E, NB, chunk);
    k_scanA    <<<mB,     BLK,  0, stream>>>(offs, bsum, m);
    k_scanB    <<<1,      1024, 0, stream>>>(bsum, boff, mB);
    k_scanC    <<<mB,     BLK,  0, stream>>>(offs, boff, m);
    k_binB     <<<G,      BLK,  0, stream>>>(src, dst, offs, words, E, NB, chunk);
    k_cnt_split<<<NB * K, BLK,  0, stream>>>(words, offs, pcnt, E, NB, K);
    k_cnt_comb <<<NB,     BLK,  0, stream>>>(pcnt, x, dinv, xd, n, K);
    k_agg_split<<<NB * K, BLK,  0, stream>>>(words, offs, xd, pagg, E, NB, K);
    k_comb1    <<<NB,     BLK,  0, stream>>>(pagg, dinv, xd, W1, b1, W2, g2, n, K);
    k_agg_split<<<NB * K, BLK,  0, stream>>>(words, offs, g2, pagg, E, NB, K);
    k_comb2    <<<NB,     BLK,  0, stream>>>(pagg, dinv, g2, b2, out, n, K);
}